// Round 4
// baseline (409.103 us; speedup 1.0000x reference)
//
#include <hip/hip_runtime.h>
#include <hip/hip_bf16.h>

#define NN 9216      // W*H
#define CCH 256      // channels
#define PSTR 76      // ps row stride (u16) — bank-spread + 8B align

typedef unsigned short u16;
typedef unsigned int   u32;
typedef __attribute__((ext_vector_type(8))) short bf16x8;   // 8 bf16 = 4 VGPRs
typedef __attribute__((ext_vector_type(4))) float f32x4;

static __device__ __forceinline__ u16 f2bf(float f){
    u32 u = __builtin_bit_cast(u32, f);
    u += 0x7fffu + ((u >> 16) & 1u);   // RNE; inputs finite
    return (u16)(u >> 16);
}
static __device__ __forceinline__ float bf2f(u16 h){
    u32 u = ((u32)h) << 16;
    return __builtin_bit_cast(float, u);
}

// ---------------- K1: fused projections (+ rsums zeroing) ----------------
// blocks 0..71:   q,k projection + center + sumsq partials; qhb/khb bf16 [n][32]
// blocks 72..359: v projection -> vb bf16 [c][m]; first 9 also zero rsums
extern "C" __global__ __launch_bounds__(256)
void proj_all(const float* __restrict__ x, const float* __restrict__ sf,
              const float* __restrict__ Wq, const float* __restrict__ bq,
              const float* __restrict__ Wk, const float* __restrict__ bk,
              const float* __restrict__ Wv, const float* __restrict__ bv,
              u16* __restrict__ qhb, u16* __restrict__ khb, u16* __restrict__ vb,
              float* __restrict__ pq, float* __restrict__ pk,
              float* __restrict__ rsums)
{
    const int bid = blockIdx.x, t = threadIdx.x;
    if (bid < 72){
        const int isk = (t >= 128);            // waves 0,1: q ; waves 2,3: k
        const int n   = bid * 128 + (t & 127);
        const float* W  = isk ? Wk : Wq;
        const float* bb = isk ? bk : bq;
        const float* in = isk ? x  : sf;
        float a[32];
        #pragma unroll
        for (int o = 0; o < 32; ++o) a[o] = bb[o];
        for (int c = 0; c < CCH; ++c){
            float v = in[c * NN + n];
            #pragma unroll
            for (int o = 0; o < 32; ++o) a[o] = fmaf(W[o * CCH + c], v, a[o]);
        }
        float mn = 0.f;
        #pragma unroll
        for (int o = 0; o < 32; ++o) mn += a[o];
        mn *= (1.f / 32.f);
        float ss = 0.f;
        #pragma unroll
        for (int o = 0; o < 32; ++o){ a[o] -= mn; ss = fmaf(a[o], a[o], ss); }
        u16* dst = (isk ? khb : qhb) + n * 32;
        #pragma unroll
        for (int i = 0; i < 32; i += 8){
            uint4 pk4;
            pk4.x = (u32)f2bf(a[i+0]) | ((u32)f2bf(a[i+1]) << 16);
            pk4.y = (u32)f2bf(a[i+2]) | ((u32)f2bf(a[i+3]) << 16);
            pk4.z = (u32)f2bf(a[i+4]) | ((u32)f2bf(a[i+5]) << 16);
            pk4.w = (u32)f2bf(a[i+6]) | ((u32)f2bf(a[i+7]) << 16);
            *reinterpret_cast<uint4*>(dst + i) = pk4;
        }
        __shared__ float red[256];
        red[t] = ss; __syncthreads();
        for (int off = 64; off > 0; off >>= 1){
            if ((t & 127) < off) red[t] += red[t + off];
            __syncthreads();
        }
        if (t == 0)   pq[bid] = red[0];
        if (t == 128) pk[bid] = red[128];
    } else {
        const int vbid = bid - 72;             // 0..287
        if (vbid < 9){                         // zero rsums (9*1024 = 9216)
            float4 z = {0.f,0.f,0.f,0.f};
            *reinterpret_cast<float4*>(rsums + (size_t)vbid * 1024 + t * 4) = z;
        }
        const int m  = vbid * 32 + (t & 31);
        const int c0 = (t >> 5) * 32;          // 8 c-groups of 32
        float acc[32];
        #pragma unroll
        for (int i = 0; i < 32; ++i) acc[i] = bv[c0 + i];
        for (int c = 0; c < CCH; ++c){
            float xv = x[c * NN + m];
            #pragma unroll
            for (int i = 0; i < 32; ++i)
                acc[i] = fmaf(Wv[(c0 + i) * CCH + c], xv, acc[i]);
        }
        #pragma unroll
        for (int i = 0; i < 32; ++i)
            vb[(c0 + i) * NN + m] = f2bf(acc[i]);
    }
}

// ---------------- K2: row sums of exp(energy) via MFMA ----------------
// grid 1152: nc = bid>>3 (64 rows), ms = bid&7 (1152 cols)
extern "C" __global__ __launch_bounds__(256)
void rowsums_k(const u16* __restrict__ qhb, const u16* __restrict__ khb,
               const float* __restrict__ pq, const float* __restrict__ pk,
               float* __restrict__ rsums)
{
    const int bid = blockIdx.x;
    const int nc = bid >> 3, ms = bid & 7;
    const int t = threadIdx.x, w = t >> 6, l = t & 63, h = l >> 4, r = l & 15;
    const int n0 = nc * 64, mbase = ms * 1152;

    float sq = 0.f, sk = 0.f;
    for (int i = 0; i < 72; ++i){ sq += pq[i]; sk += pk[i]; }
    const float inv_den = rsqrtf(sq) * rsqrtf(sk);

    bf16x8 qf[4];
    #pragma unroll
    for (int nt = 0; nt < 4; ++nt)
        qf[nt] = *reinterpret_cast<const bf16x8*>(qhb + (n0 + nt*16 + r)*32 + 8*h);

    float racc[4][4];
    #pragma unroll
    for (int nt = 0; nt < 4; ++nt)
        #pragma unroll
        for (int g2 = 0; g2 < 4; ++g2) racc[nt][g2] = 0.f;

    for (int i = 0; i < 18; ++i){
        const int mcol = mbase + (w + 4*i) * 16;
        bf16x8 kf = *reinterpret_cast<const bf16x8*>(khb + (mcol + r)*32 + 8*h);
        #pragma unroll
        for (int nt = 0; nt < 4; ++nt){
            f32x4 z = {0.f,0.f,0.f,0.f};
            f32x4 e = __builtin_amdgcn_mfma_f32_16x16x32_bf16(qf[nt], kf, z, 0, 0, 0);
            #pragma unroll
            for (int g2 = 0; g2 < 4; ++g2)
                racc[nt][g2] += __expf(e[g2] * inv_den);
        }
    }
    #pragma unroll
    for (int mask = 1; mask <= 8; mask <<= 1)
        #pragma unroll
        for (int nt = 0; nt < 4; ++nt)
            #pragma unroll
            for (int g2 = 0; g2 < 4; ++g2)
                racc[nt][g2] += __shfl_xor(racc[nt][g2], mask);

    if (r == 0){
        #pragma unroll
        for (int nt = 0; nt < 4; ++nt)
            #pragma unroll
            for (int g2 = 0; g2 < 4; ++g2)
                atomicAdd(rsums + n0 + nt*16 + 4*h + g2, racc[nt][g2]);
    }
}

// ---------------- K3: attention write + PV, pipelined ----------------
// grid 1152: nc = bid>>3 (64 n-rows), ms = bid&7 (1152 m-cols); 18 m-tiles of 64
extern "C" __global__ __launch_bounds__(256)
void attn_main(const u16* __restrict__ qhb, const u16* __restrict__ khb,
               const u16* __restrict__ vb,
               const float* __restrict__ pq, const float* __restrict__ pk,
               const float* __restrict__ rsums,
               float* __restrict__ outdst, float* __restrict__ attnf,
               int use_atomic)
{
    __shared__ u16 ps[2][64 * PSTR];
    const int bid = blockIdx.x;
    const int nc = bid >> 3, ms = bid & 7;
    const int t = threadIdx.x, w = t >> 6, l = t & 63, h = l >> 4, r = l & 15;
    const int n0 = nc * 64, mbase = ms * 1152;

    float sq = 0.f, sk = 0.f;
    for (int i = 0; i < 72; ++i){ sq += pq[i]; sk += pk[i]; }
    const float inv_den = rsqrtf(sq) * rsqrtf(sk);

    bf16x8 qf[4];
    #pragma unroll
    for (int nt = 0; nt < 4; ++nt)
        qf[nt] = *reinterpret_cast<const bf16x8*>(qhb + (n0 + nt*16 + r)*32 + 8*h);

    float rinv[4][4];
    #pragma unroll
    for (int nt = 0; nt < 4; ++nt)
        #pragma unroll
        for (int g2 = 0; g2 < 4; ++g2)
            rinv[nt][g2] = 1.f / rsums[n0 + nt*16 + 4*h + g2];

    f32x4 acc[4][4];
    #pragma unroll
    for (int ct = 0; ct < 4; ++ct)
        #pragma unroll
        for (int nt = 0; nt < 4; ++nt)
            acc[ct][nt] = (f32x4){0.f,0.f,0.f,0.f};

    // STAGE: QK -> exp -> normalized P (bf16) into ps[buf]
    auto STAGE = [&](int mt){
        const int buf = mt & 1;
        const int m0s = mbase + mt * 64;
        bf16x8 kf = *reinterpret_cast<const bf16x8*>(khb + (m0s + w*16 + r)*32 + 8*h);
        #pragma unroll
        for (int nt = 0; nt < 4; ++nt){
            f32x4 z = {0.f,0.f,0.f,0.f};
            f32x4 e = __builtin_amdgcn_mfma_f32_16x16x32_bf16(qf[nt], kf, z, 0, 0, 0);
            #pragma unroll
            for (int g2 = 0; g2 < 4; ++g2){
                float p = __expf(e[g2] * inv_den) * rinv[nt][g2];
                ps[buf][(nt*16 + 4*h + g2) * PSTR + w*16 + r] = f2bf(p);
            }
        }
    };

    STAGE(0);
    __syncthreads();

    const int arow_i = t >> 2;            // 0..63
    const int acb    = (t & 3) * 16;      // col block

    for (int mt = 0; mt < 18; ++mt){
        if (mt < 17) STAGE(mt + 1);
        const int buf = mt & 1;
        const int m0  = mbase + mt * 64;

        // coalesced attention write from LDS bf16 tile
        {
            const u16* prow = &ps[buf][arow_i * PSTR + acb];
            float* arow = attnf + (size_t)(n0 + arow_i) * NN + m0 + acb;
            #pragma unroll
            for (int j = 0; j < 4; ++j){
                ushort4 u = *reinterpret_cast<const ushort4*>(prow + j*4);
                float4 f4;
                f4.x = bf2f(u.x); f4.y = bf2f(u.y);
                f4.z = bf2f(u.z); f4.w = bf2f(u.w);
                *reinterpret_cast<float4*>(arow + j*4) = f4;
            }
        }

        // PV: D[c][n] += vb[c][m-tile] * P^T[m-tile][n]
        #pragma unroll
        for (int ks = 0; ks < 2; ++ks){
            bf16x8 av[4];
            #pragma unroll
            for (int ct = 0; ct < 4; ++ct)
                av[ct] = *reinterpret_cast<const bf16x8*>(
                    vb + (w*64 + ct*16 + r) * NN + m0 + ks*32 + 8*h);
            bf16x8 bv2[4];
            #pragma unroll
            for (int nt = 0; nt < 4; ++nt)
                bv2[nt] = *reinterpret_cast<const bf16x8*>(
                    &ps[buf][(nt*16 + r) * PSTR + ks*32 + 8*h]);
            #pragma unroll
            for (int ct = 0; ct < 4; ++ct)
                #pragma unroll
                for (int nt = 0; nt < 4; ++nt)
                    acc[ct][nt] = __builtin_amdgcn_mfma_f32_16x16x32_bf16(
                        av[ct], bv2[nt], acc[ct][nt], 0, 0, 0);
        }
        __syncthreads();
    }

    if (!use_atomic){
        float* dst = outdst + (size_t)ms * (CCH * NN);
        #pragma unroll
        for (int ct = 0; ct < 4; ++ct)
            #pragma unroll
            for (int nt = 0; nt < 4; ++nt)
                #pragma unroll
                for (int g2 = 0; g2 < 4; ++g2)
                    dst[(w*64 + ct*16 + 4*h + g2) * NN + n0 + nt*16 + r] =
                        acc[ct][nt][g2];
    } else {
        #pragma unroll
        for (int ct = 0; ct < 4; ++ct)
            #pragma unroll
            for (int nt = 0; nt < 4; ++nt)
                #pragma unroll
                for (int g2 = 0; g2 < 4; ++g2)
                    atomicAdd(outdst + (w*64 + ct*16 + 4*h + g2) * NN + n0 + nt*16 + r,
                              acc[ct][nt][g2]);
    }
}

// ---------------- K4: out = gamma*(sum partials) + x ----------------
extern "C" __global__ __launch_bounds__(256)
void epilogue(const float* __restrict__ x, const float* __restrict__ gm,
              const float* __restrict__ parts, int nparts,
              float* __restrict__ outf)
{
    const float g = gm[0];
    const size_t i = ((size_t)blockIdx.x * 256 + threadIdx.x) * 4;
    float4 a;
    if (nparts > 0){
        a.x = a.y = a.z = a.w = 0.f;
        for (int s = 0; s < nparts; ++s){
            float4 p = *reinterpret_cast<const float4*>(parts + (size_t)s * (CCH*NN) + i);
            a.x += p.x; a.y += p.y; a.z += p.z; a.w += p.w;
        }
    } else {
        a = *reinterpret_cast<float4*>(outf + i);
    }
    float4 xv = *reinterpret_cast<const float4*>(x + i);
    a.x = fmaf(g, a.x, xv.x);
    a.y = fmaf(g, a.y, xv.y);
    a.z = fmaf(g, a.z, xv.z);
    a.w = fmaf(g, a.w, xv.w);
    *reinterpret_cast<float4*>(outf + i) = a;
}

// ---------------- zero helper (atomic fallback only) ----------------
extern "C" __global__ __launch_bounds__(256)
void zero_buf(float* __restrict__ p)
{
    float4 z = {0.f,0.f,0.f,0.f};
    *reinterpret_cast<float4*>(p + ((size_t)blockIdx.x * 256 + threadIdx.x) * 4) = z;
}

extern "C" void kernel_launch(void* const* d_in, const int* in_sizes, int n_in,
                              void* d_out, int out_size, void* d_ws, size_t ws_size,
                              hipStream_t stream)
{
    (void)in_sizes; (void)n_in; (void)out_size;
    const float* x  = (const float*)d_in[0];
    const float* sf = (const float*)d_in[1];
    const float* Wq = (const float*)d_in[2];
    const float* bq = (const float*)d_in[3];
    const float* Wk = (const float*)d_in[4];
    const float* bk = (const float*)d_in[5];
    const float* Wv = (const float*)d_in[6];
    const float* bv = (const float*)d_in[7];
    const float* gm = (const float*)d_in[8];

    float* outf  = (float*)d_out;                       // [256][9216] f32
    float* attnf = outf + (size_t)256 * 9216;           // [9216][9216] f32

    char* ws = (char*)d_ws;
    u16*   qhb   = (u16*)(ws);                          // 589,824 B
    u16*   khb   = (u16*)(ws + 589824);                 // 589,824 B
    u16*   vbp   = (u16*)(ws + 1179648);                // 4,718,592 B
    float* rsums = (float*)(ws + 5898240);              // 36,864 B
    float* pq    = (float*)(ws + 5935104);              // 288 B
    float* pk    = (float*)(ws + 5935392);              // 288 B
    float* parts = (float*)(ws + 5935872);              // 8 * 9,437,184 B
    const size_t need = 5935872ull + 8ull * 9437184ull; // 81,433,344

    const bool use_parts = (ws_size >= need);

    proj_all <<<dim3(360),  dim3(256), 0, stream>>>(x, sf, Wq, bq, Wk, bk, Wv, bv,
                                                    qhb, khb, vbp, pq, pk, rsums);
    if (!use_parts)
        zero_buf<<<dim3(2304), dim3(256), 0, stream>>>(outf);
    rowsums_k<<<dim3(1152), dim3(256), 0, stream>>>(qhb, khb, pq, pk, rsums);
    attn_main<<<dim3(1152), dim3(256), 0, stream>>>(qhb, khb, vbp, pq, pk, rsums,
                                                    use_parts ? parts : outf, attnf,
                                                    use_parts ? 0 : 1);
    epilogue <<<dim3(2304), dim3(256), 0, stream>>>(x, gm, parts,
                                                    use_parts ? 8 : 0, outf);
}

// Round 5
// 392.952 us; speedup vs baseline: 1.0411x; 1.0411x over previous
//
#include <hip/hip_runtime.h>
#include <hip/hip_bf16.h>

#define NN 9216      // W*H
#define CCH 256      // channels
#define PSTR 76      // ps row stride (u16) — bank-spread, 8B-aligned rows

typedef unsigned short u16;
typedef unsigned int   u32;
typedef __attribute__((ext_vector_type(8))) short bf16x8;   // 8 bf16 = 4 VGPRs
typedef __attribute__((ext_vector_type(4))) float f32x4;

static __device__ __forceinline__ u16 f2bf(float f){
    u32 u = __builtin_bit_cast(u32, f);
    u += 0x7fffu + ((u >> 16) & 1u);   // RNE; inputs finite
    return (u16)(u >> 16);
}
static __device__ __forceinline__ float bf2f(u16 h){
    u32 u = ((u32)h) << 16;
    return __builtin_bit_cast(float, u);
}

// ---------------- K1: fused projections (+ S2/ksum zeroing) ----------------
// blocks 0..71:   q,k projection + center + sumsq partials; qhb/khb bf16 [n][32]
// blocks 72..359: v projection -> vb bf16 [c][m]; block 72 zeroes S2/ksum
extern "C" __global__ __launch_bounds__(256)
void proj_all(const float* __restrict__ x, const float* __restrict__ sf,
              const float* __restrict__ Wq, const float* __restrict__ bq,
              const float* __restrict__ Wk, const float* __restrict__ bk,
              const float* __restrict__ Wv, const float* __restrict__ bv,
              u16* __restrict__ qhb, u16* __restrict__ khb, u16* __restrict__ vb,
              float* __restrict__ pq, float* __restrict__ pk,
              float* __restrict__ S2, float* __restrict__ ksum)
{
    const int bid = blockIdx.x, t = threadIdx.x;
    if (bid < 72){
        const int isk = (t >= 128);            // waves 0,1: q ; waves 2,3: k
        const int n   = bid * 128 + (t & 127);
        const float* W  = isk ? Wk : Wq;
        const float* bb = isk ? bk : bq;
        const float* in = isk ? x  : sf;
        float a[32];
        #pragma unroll
        for (int o = 0; o < 32; ++o) a[o] = bb[o];
        for (int c = 0; c < CCH; ++c){
            float v = in[c * NN + n];
            #pragma unroll
            for (int o = 0; o < 32; ++o) a[o] = fmaf(W[o * CCH + c], v, a[o]);
        }
        float mn = 0.f;
        #pragma unroll
        for (int o = 0; o < 32; ++o) mn += a[o];
        mn *= (1.f / 32.f);
        float ss = 0.f;
        u16* dst = (isk ? khb : qhb) + n * 32;
        #pragma unroll
        for (int i = 0; i < 32; i += 8){
            uint4 pk4;
            u16 h0,h1,h2,h3,h4,h5,h6,h7;
            h0=f2bf(a[i+0]-mn); h1=f2bf(a[i+1]-mn); h2=f2bf(a[i+2]-mn); h3=f2bf(a[i+3]-mn);
            h4=f2bf(a[i+4]-mn); h5=f2bf(a[i+5]-mn); h6=f2bf(a[i+6]-mn); h7=f2bf(a[i+7]-mn);
            // sumsq on the ROUNDED values (consistent with what MFMA consumes)
            float r0=bf2f(h0),r1=bf2f(h1),r2=bf2f(h2),r3=bf2f(h3);
            float r4=bf2f(h4),r5=bf2f(h5),r6=bf2f(h6),r7=bf2f(h7);
            ss = fmaf(r0,r0,ss); ss = fmaf(r1,r1,ss); ss = fmaf(r2,r2,ss); ss = fmaf(r3,r3,ss);
            ss = fmaf(r4,r4,ss); ss = fmaf(r5,r5,ss); ss = fmaf(r6,r6,ss); ss = fmaf(r7,r7,ss);
            pk4.x = (u32)h0 | ((u32)h1 << 16);
            pk4.y = (u32)h2 | ((u32)h3 << 16);
            pk4.z = (u32)h4 | ((u32)h5 << 16);
            pk4.w = (u32)h6 | ((u32)h7 << 16);
            *reinterpret_cast<uint4*>(dst + i) = pk4;
        }
        __shared__ float red[256];
        red[t] = ss; __syncthreads();
        for (int off = 64; off > 0; off >>= 1){
            if ((t & 127) < off) red[t] += red[t + off];
            __syncthreads();
        }
        if (t == 0)   pq[bid] = red[0];
        if (t == 128) pk[bid] = red[128];
    } else {
        const int vbid = bid - 72;             // 0..287
        if (vbid == 0){                        // zero S2 (1024) + ksum (32)
            #pragma unroll
            for (int k2 = 0; k2 < 4; ++k2) S2[t + 256*k2] = 0.f;
            if (t < 32) ksum[t] = 0.f;
        }
        const int m  = vbid * 32 + (t & 31);
        const int c0 = (t >> 5) * 32;          // 8 c-groups of 32
        float acc[32];
        #pragma unroll
        for (int i = 0; i < 32; ++i) acc[i] = bv[c0 + i];
        for (int c = 0; c < CCH; ++c){
            float xv = x[c * NN + m];
            #pragma unroll
            for (int i = 0; i < 32; ++i)
                acc[i] = fmaf(Wv[(c0 + i) * CCH + c], xv, acc[i]);
        }
        #pragma unroll
        for (int i = 0; i < 32; ++i)
            vb[(c0 + i) * NN + m] = f2bf(acc[i]);
    }
}

// ---------------- K2: S2 = K̂ᵀK̂ and ksum = Σ k̂  ----------------
// grid 256 blocks, 36 m-rows each
extern "C" __global__ __launch_bounds__(256)
void s2k(const u16* __restrict__ khb, float* __restrict__ S2,
         float* __restrict__ ksum)
{
    __shared__ float ks[36][33];
    const int t = threadIdx.x;
    const int m0 = blockIdx.x * 36;
    if (t < 144){
        const int row = t >> 2, seg = (t & 3) * 8;
        bf16x8 v = *reinterpret_cast<const bf16x8*>(khb + (m0 + row) * 32 + seg);
        #pragma unroll
        for (int j = 0; j < 8; ++j)
            ks[row][seg + j] = bf2f((u16)v[j]);
    }
    __syncthreads();
    #pragma unroll
    for (int k2 = 0; k2 < 4; ++k2){
        const int task = t + 256 * k2;         // 0..1023
        const int i = task >> 5, j = task & 31;
        float s = 0.f;
        for (int m = 0; m < 36; ++m)
            s = fmaf(ks[m][i], ks[m][j], s);
        atomicAdd(S2 + task, s);
    }
    if (t < 32){
        float s = 0.f;
        for (int m = 0; m < 36; ++m) s += ks[m][t];
        atomicAdd(ksum + t, s);
    }
}

// ---------------- K3: per-row Taylor rowsum -> rinv ----------------
// rowsum_n = N + (q·ksum)*d + 0.5*(qᵀS2q)*d²   (exp Taylor, |e|<2e-4)
extern "C" __global__ __launch_bounds__(256)
void rowfin(const u16* __restrict__ qhb, const float* __restrict__ S2,
            const float* __restrict__ ksum,
            const float* __restrict__ pq, const float* __restrict__ pk,
            float* __restrict__ rinv_arr)
{
    __shared__ float s2s[1024];
    __shared__ float kss[32];
    const int t = threadIdx.x;
    #pragma unroll
    for (int k2 = 0; k2 < 4; ++k2) s2s[t + 256*k2] = S2[t + 256*k2];
    if (t < 32) kss[t] = ksum[t];
    __syncthreads();

    float sq = 0.f, sk = 0.f;
    for (int i = 0; i < 72; ++i){ sq += pq[i]; sk += pk[i]; }
    const float d = rsqrtf(sq) * rsqrtf(sk);

    const int n = blockIdx.x * 256 + t;
    float q[32];
    #pragma unroll
    for (int s8 = 0; s8 < 4; ++s8){
        bf16x8 v = *reinterpret_cast<const bf16x8*>(qhb + n * 32 + s8 * 8);
        #pragma unroll
        for (int j = 0; j < 8; ++j) q[s8*8 + j] = bf2f((u16)v[j]);
    }
    float d1 = 0.f;
    #pragma unroll
    for (int o = 0; o < 32; ++o) d1 = fmaf(q[o], kss[o], d1);
    float quad = 0.f;
    for (int o = 0; o < 32; ++o){
        float s = 0.f;
        #pragma unroll
        for (int j = 0; j < 32; ++j) s = fmaf(s2s[o*32 + j], q[j], s);
        quad = fmaf(q[o], s, quad);
    }
    const float rs = 9216.f + d1 * d + 0.5f * quad * d * d;
    rinv_arr[n] = 1.f / rs;
}

// ---------------- K4: attention write + PV, Taylor-exp, nt=2 ----------------
// grid 2304: nc = bid>>3 (32 n-rows), ms = bid&7 (1152 m-cols); 18 m-tiles of 64
extern "C" __global__ __launch_bounds__(256, 4)
void attn_main(const u16* __restrict__ qhb, const u16* __restrict__ khb,
               const u16* __restrict__ vb,
               const float* __restrict__ pq, const float* __restrict__ pk,
               const float* __restrict__ rinv_arr,
               float* __restrict__ outdst, float* __restrict__ attnf,
               int use_atomic)
{
    __shared__ u16 ps[2][32 * PSTR];
    const int bid = blockIdx.x;
    const int nc = bid >> 3, ms = bid & 7;
    const int t = threadIdx.x, w = t >> 6, l = t & 63, h = l >> 4, r = l & 15;
    const int n0 = nc * 32, mbase = ms * 1152;

    float sq = 0.f, sk = 0.f;
    for (int i = 0; i < 72; ++i){ sq += pq[i]; sk += pk[i]; }
    const float inv_den = rsqrtf(sq) * rsqrtf(sk);

    bf16x8 qf[2];
    #pragma unroll
    for (int nt = 0; nt < 2; ++nt)
        qf[nt] = *reinterpret_cast<const bf16x8*>(qhb + (n0 + nt*16 + r)*32 + 8*h);

    float rinv8[2][4];
    #pragma unroll
    for (int nt = 0; nt < 2; ++nt)
        #pragma unroll
        for (int g2 = 0; g2 < 4; ++g2)
            rinv8[nt][g2] = rinv_arr[n0 + nt*16 + 4*h + g2];

    f32x4 acc[4][2];
    #pragma unroll
    for (int ct = 0; ct < 4; ++ct)
        #pragma unroll
        for (int nt = 0; nt < 2; ++nt)
            acc[ct][nt] = (f32x4){0.f,0.f,0.f,0.f};

    // STAGE: QK -> Taylor exp -> normalized P (bf16) into ps[buf]
    auto STAGE = [&](int mt){
        const int buf = mt & 1;
        const int m0s = mbase + mt * 64;
        bf16x8 kf = *reinterpret_cast<const bf16x8*>(khb + (m0s + w*16 + r)*32 + 8*h);
        #pragma unroll
        for (int nt = 0; nt < 2; ++nt){
            f32x4 z = {0.f,0.f,0.f,0.f};
            f32x4 e = __builtin_amdgcn_mfma_f32_16x16x32_bf16(qf[nt], kf, z, 0, 0, 0);
            #pragma unroll
            for (int g2 = 0; g2 < 4; ++g2){
                float ep = e[g2] * inv_den;
                float p  = fmaf(ep, fmaf(0.5f, ep, 1.f), 1.f) * rinv8[nt][g2];
                ps[buf][(nt*16 + 4*h + g2) * PSTR + w*16 + r] = f2bf(p);
            }
        }
    };

    STAGE(0);
    __syncthreads();

    const int trow = t >> 3;              // 0..31
    const int tcol = (t & 7) * 8;         // col block (8 f32)

    for (int mt = 0; mt < 18; ++mt){
        if (mt < 17) STAGE(mt + 1);
        const int buf = mt & 1;
        const int m0  = mbase + mt * 64;

        // coalesced attention write from LDS bf16 tile
        {
            const u16* prow = &ps[buf][trow * PSTR + tcol];
            float* arow = attnf + (size_t)(n0 + trow) * NN + m0 + tcol;
            #pragma unroll
            for (int j = 0; j < 2; ++j){
                ushort4 u = *reinterpret_cast<const ushort4*>(prow + j*4);
                float4 f4;
                f4.x = bf2f(u.x); f4.y = bf2f(u.y);
                f4.z = bf2f(u.z); f4.w = bf2f(u.w);
                *reinterpret_cast<float4*>(arow + j*4) = f4;
            }
        }

        // PV: D[c][n] += vb[c][m-tile] * P^T[m-tile][n]
        #pragma unroll
        for (int ks = 0; ks < 2; ++ks){
            bf16x8 av[4];
            #pragma unroll
            for (int ct = 0; ct < 4; ++ct)
                av[ct] = *reinterpret_cast<const bf16x8*>(
                    vb + (w*64 + ct*16 + r) * NN + m0 + ks*32 + 8*h);
            bf16x8 bv2[2];
            #pragma unroll
            for (int nt = 0; nt < 2; ++nt)
                bv2[nt] = *reinterpret_cast<const bf16x8*>(
                    &ps[buf][(nt*16 + r) * PSTR + ks*32 + 8*h]);
            #pragma unroll
            for (int ct = 0; ct < 4; ++ct)
                #pragma unroll
                for (int nt = 0; nt < 2; ++nt)
                    acc[ct][nt] = __builtin_amdgcn_mfma_f32_16x16x32_bf16(
                        av[ct], bv2[nt], acc[ct][nt], 0, 0, 0);
        }
        __syncthreads();
    }

    if (!use_atomic){
        float* dst = outdst + (size_t)ms * (CCH * NN);
        #pragma unroll
        for (int ct = 0; ct < 4; ++ct)
            #pragma unroll
            for (int nt = 0; nt < 2; ++nt)
                #pragma unroll
                for (int g2 = 0; g2 < 4; ++g2)
                    dst[(w*64 + ct*16 + 4*h + g2) * NN + n0 + nt*16 + r] =
                        acc[ct][nt][g2];
    } else {
        #pragma unroll
        for (int ct = 0; ct < 4; ++ct)
            #pragma unroll
            for (int nt = 0; nt < 2; ++nt)
                #pragma unroll
                for (int g2 = 0; g2 < 4; ++g2)
                    atomicAdd(outdst + (w*64 + ct*16 + 4*h + g2) * NN + n0 + nt*16 + r,
                              acc[ct][nt][g2]);
    }
}

// ---------------- K5: out = gamma*(sum partials) + x ----------------
extern "C" __global__ __launch_bounds__(256)
void epilogue(const float* __restrict__ x, const float* __restrict__ gm,
              const float* __restrict__ parts, int nparts,
              float* __restrict__ outf)
{
    const float g = gm[0];
    const size_t i = ((size_t)blockIdx.x * 256 + threadIdx.x) * 4;
    float4 a;
    if (nparts > 0){
        a.x = a.y = a.z = a.w = 0.f;
        for (int s = 0; s < nparts; ++s){
            float4 p = *reinterpret_cast<const float4*>(parts + (size_t)s * (CCH*NN) + i);
            a.x += p.x; a.y += p.y; a.z += p.z; a.w += p.w;
        }
    } else {
        a = *reinterpret_cast<float4*>(outf + i);
    }
    float4 xv = *reinterpret_cast<const float4*>(x + i);
    a.x = fmaf(g, a.x, xv.x);
    a.y = fmaf(g, a.y, xv.y);
    a.z = fmaf(g, a.z, xv.z);
    a.w = fmaf(g, a.w, xv.w);
    *reinterpret_cast<float4*>(outf + i) = a;
}

// ---------------- zero helper (atomic fallback only) ----------------
extern "C" __global__ __launch_bounds__(256)
void zero_buf(float* __restrict__ p)
{
    float4 z = {0.f,0.f,0.f,0.f};
    *reinterpret_cast<float4*>(p + ((size_t)blockIdx.x * 256 + threadIdx.x) * 4) = z;
}

extern "C" void kernel_launch(void* const* d_in, const int* in_sizes, int n_in,
                              void* d_out, int out_size, void* d_ws, size_t ws_size,
                              hipStream_t stream)
{
    (void)in_sizes; (void)n_in; (void)out_size;
    const float* x  = (const float*)d_in[0];
    const float* sf = (const float*)d_in[1];
    const float* Wq = (const float*)d_in[2];
    const float* bq = (const float*)d_in[3];
    const float* Wk = (const float*)d_in[4];
    const float* bk = (const float*)d_in[5];
    const float* Wv = (const float*)d_in[6];
    const float* bv = (const float*)d_in[7];
    const float* gm = (const float*)d_in[8];

    float* outf  = (float*)d_out;                       // [256][9216] f32
    float* attnf = outf + (size_t)256 * 9216;           // [9216][9216] f32

    char* ws = (char*)d_ws;
    u16*   qhb   = (u16*)(ws);                          // 589,824 B
    u16*   khb   = (u16*)(ws + 589824);                 // 589,824 B
    u16*   vbp   = (u16*)(ws + 1179648);                // 4,718,592 B
    float* pq    = (float*)(ws + 5898240);              // 288 B
    float* pk    = (float*)(ws + 5898528);              // 288 B
    float* S2    = (float*)(ws + 5898816);              // 4,096 B
    float* ksum  = (float*)(ws + 5902912);              // 128 B
    float* rinv  = (float*)(ws + 5903040);              // 36,864 B
    float* parts = (float*)(ws + 5940224);              // 8 * 9,437,184 B
    const size_t need = 5940224ull + 8ull * 9437184ull; // 81,437,696

    const bool use_parts = (ws_size >= need);

    proj_all <<<dim3(360),  dim3(256), 0, stream>>>(x, sf, Wq, bq, Wk, bk, Wv, bv,
                                                    qhb, khb, vbp, pq, pk, S2, ksum);
    s2k      <<<dim3(256),  dim3(256), 0, stream>>>(khb, S2, ksum);
    rowfin   <<<dim3(36),   dim3(256), 0, stream>>>(qhb, S2, ksum, pq, pk, rinv);
    if (!use_parts)
        zero_buf<<<dim3(2304), dim3(256), 0, stream>>>(outf);
    attn_main<<<dim3(2304), dim3(256), 0, stream>>>(qhb, khb, vbp, pq, pk, rinv,
                                                    use_parts ? parts : outf, attnf,
                                                    use_parts ? 0 : 1);
    epilogue <<<dim3(2304), dim3(256), 0, stream>>>(x, gm, parts,
                                                    use_parts ? 8 : 0, outf);
}

// Round 6
// 221.704 us; speedup vs baseline: 1.8453x; 1.7724x over previous
//
#include <hip/hip_runtime.h>
#include <hip/hip_bf16.h>

#define NN 9216      // W*H
#define CCH 256      // channels
#define PS2 268      // attn ps row stride (u16): dw stride 134 (%32==6) — conflict-checked
#define CTS 268      // castT LDS row stride (u16)

typedef unsigned short u16;
typedef unsigned int   u32;
typedef __attribute__((ext_vector_type(8))) short bf16x8;   // 8 bf16 = 4 VGPRs
typedef __attribute__((ext_vector_type(4))) float f32x4;

static __device__ __forceinline__ u16 f2bf(float f){
    u32 u = __builtin_bit_cast(u32, f);
    u += 0x7fffu + ((u >> 16) & 1u);   // RNE; inputs finite
    return (u16)(u >> 16);
}
static __device__ __forceinline__ float bf2f(u16 h){
    u32 u = ((u32)h) << 16;
    return __builtin_bit_cast(float, u);
}

// ---------------- K0: cast+transpose x,sf -> [n][c] bf16; cast W's ----------
// bids 0..143: xT chunks; 144..287: sfT chunks; 288..295: W cast (+zero S2/ksum)
extern "C" __global__ __launch_bounds__(256)
void castT(const float* __restrict__ x, const float* __restrict__ sf,
           const float* __restrict__ Wq, const float* __restrict__ Wk,
           const float* __restrict__ Wv,
           u16* __restrict__ xT, u16* __restrict__ sfT,
           u16* __restrict__ wqb, u16* __restrict__ wkb, u16* __restrict__ wvb,
           float* __restrict__ S2, float* __restrict__ ksum)
{
    const int bid = blockIdx.x, t = threadIdx.x;
    if (bid < 288){
        __shared__ u16 ls[64 * CTS];
        const int isf = bid >= 144;
        const int n0 = (isf ? bid - 144 : bid) * 64;
        const float* src = isf ? sf : x;
        const int nl = t & 63;
        const int cg = t >> 6;          // 0..3
        for (int i = 0; i < 64; ++i){
            int c = cg * 64 + i;
            float v = src[(size_t)c * NN + n0 + nl];
            ls[nl * CTS + c] = f2bf(v);
        }
        __syncthreads();
        u16* dst = (isf ? sfT : xT) + (size_t)(n0 + nl) * 256 + cg * 64;
        const u16* lrow = &ls[nl * CTS + cg * 64];
        #pragma unroll
        for (int j = 0; j < 8; ++j){
            uint2 p = *reinterpret_cast<const uint2*>(lrow + j*8);
            uint2 q = *reinterpret_cast<const uint2*>(lrow + j*8 + 4);
            uint4 o; o.x = p.x; o.y = p.y; o.z = q.x; o.w = q.y;
            *reinterpret_cast<uint4*>(dst + j*8) = o;
        }
    } else {
        const int wb = bid - 288;       // 0..7
        if (wb == 0){
            #pragma unroll
            for (int k2 = 0; k2 < 4; ++k2) S2[t + 256*k2] = 0.f;
            if (t < 32) ksum[t] = 0.f;
        }
        for (int i = 0; i < 40; ++i){
            int idx = wb * 10240 + i * 256 + t;
            if (idx < 8192)        wqb[idx]         = f2bf(Wq[idx]);
            else if (idx < 16384)  wkb[idx - 8192]  = f2bf(Wk[idx - 8192]);
            else                   wvb[idx - 16384] = f2bf(Wv[idx - 16384]);
        }
    }
}

// ---------------- K1: q,k projection via MFMA + center + sumsq --------------
// grid 72; block covers 128 n. wave w: proj = w>>1 (0:q from sf, 1:k from x),
// n-half = w&1. Wave computes [32 o][64 n].
extern "C" __global__ __launch_bounds__(256)
void qk_gemm(const u16* __restrict__ xT, const u16* __restrict__ sfT,
             const u16* __restrict__ wqb, const u16* __restrict__ wkb,
             const float* __restrict__ bq, const float* __restrict__ bk,
             u16* __restrict__ qhb, u16* __restrict__ khb,
             float* __restrict__ pq, float* __restrict__ pk)
{
    __shared__ float wsum[2][2];
    const int bid = blockIdx.x, t = threadIdx.x;
    const int w = t >> 6, l = t & 63, h = l >> 4, r = l & 15;
    const int isk = w >> 1, wn = w & 1;
    const int n0 = bid * 128 + wn * 64;
    const u16* B = isk ? xT : sfT;
    const u16* A = isk ? wkb : wqb;
    const float* bias = isk ? bk : bq;

    f32x4 acc[2][4];
    #pragma unroll
    for (int ot = 0; ot < 2; ++ot)
        #pragma unroll
        for (int nt = 0; nt < 4; ++nt) acc[ot][nt] = (f32x4){0.f,0.f,0.f,0.f};

    for (int ks = 0; ks < 8; ++ks){
        bf16x8 a0 = *reinterpret_cast<const bf16x8*>(A + (r     )*256 + ks*32 + 8*h);
        bf16x8 a1 = *reinterpret_cast<const bf16x8*>(A + (16 + r)*256 + ks*32 + 8*h);
        #pragma unroll
        for (int nt = 0; nt < 4; ++nt){
            bf16x8 b = *reinterpret_cast<const bf16x8*>(
                B + (size_t)(n0 + nt*16 + r)*256 + ks*32 + 8*h);
            acc[0][nt] = __builtin_amdgcn_mfma_f32_16x16x32_bf16(a0, b, acc[0][nt], 0,0,0);
            acc[1][nt] = __builtin_amdgcn_mfma_f32_16x16x32_bf16(a1, b, acc[1][nt], 0,0,0);
        }
    }
    float bs[2][4];
    #pragma unroll
    for (int ot = 0; ot < 2; ++ot)
        #pragma unroll
        for (int g = 0; g < 4; ++g) bs[ot][g] = bias[ot*16 + 4*h + g];

    u16* outb = (isk ? khb : qhb);
    float ssl = 0.f;
    #pragma unroll
    for (int nt = 0; nt < 4; ++nt){
        float loc = 0.f;
        #pragma unroll
        for (int ot = 0; ot < 2; ++ot)
            #pragma unroll
            for (int g = 0; g < 4; ++g){
                acc[ot][nt][g] += bs[ot][g];
                loc += acc[ot][nt][g];
            }
        loc += __shfl_xor(loc, 16);
        loc += __shfl_xor(loc, 32);
        const float mn = loc * (1.f/32.f);
        u16* dstp = outb + (size_t)(n0 + nt*16 + r) * 32;
        #pragma unroll
        for (int ot = 0; ot < 2; ++ot)
            #pragma unroll
            for (int g = 0; g < 4; ++g){
                u16 hb = f2bf(acc[ot][nt][g] - mn);
                float rv = bf2f(hb);
                ssl = fmaf(rv, rv, ssl);
                dstp[ot*16 + 4*h + g] = hb;
            }
    }
    #pragma unroll
    for (int mask = 1; mask <= 32; mask <<= 1) ssl += __shfl_xor(ssl, mask);
    if (l == 0) wsum[isk][wn] = ssl;
    __syncthreads();
    if (t == 0) pq[bid] = wsum[0][0] + wsum[0][1];
    if (t == 1) pk[bid] = wsum[1][0] + wsum[1][1];
}

// ---------------- K2: v projection via MFMA -> vb bf16 [c][m] ---------------
// grid 576: m0 = (bid>>2)*64, c0 = (bid&3)*64; wave w: c rows c0+w*16..+15
extern "C" __global__ __launch_bounds__(256)
void v_gemm(const u16* __restrict__ xT, const u16* __restrict__ wvb,
            const float* __restrict__ bv, u16* __restrict__ vb)
{
    const int bid = blockIdx.x, t = threadIdx.x;
    const int w = t >> 6, l = t & 63, h = l >> 4, r = l & 15;
    const int m0 = (bid >> 2) * 64, c0 = (bid & 3) * 64;

    f32x4 acc[4];
    #pragma unroll
    for (int nt = 0; nt < 4; ++nt) acc[nt] = (f32x4){0.f,0.f,0.f,0.f};

    for (int ks = 0; ks < 8; ++ks){
        bf16x8 a = *reinterpret_cast<const bf16x8*>(wvb + (c0 + w*16 + r)*256 + ks*32 + 8*h);
        #pragma unroll
        for (int nt = 0; nt < 4; ++nt){
            bf16x8 b = *reinterpret_cast<const bf16x8*>(
                xT + (size_t)(m0 + nt*16 + r)*256 + ks*32 + 8*h);
            acc[nt] = __builtin_amdgcn_mfma_f32_16x16x32_bf16(a, b, acc[nt], 0,0,0);
        }
    }
    float bvv[4];
    #pragma unroll
    for (int g = 0; g < 4; ++g) bvv[g] = bv[c0 + w*16 + 4*h + g];
    #pragma unroll
    for (int nt = 0; nt < 4; ++nt)
        #pragma unroll
        for (int g = 0; g < 4; ++g)
            vb[(size_t)(c0 + w*16 + 4*h + g) * NN + m0 + nt*16 + r] =
                f2bf(acc[nt][g] + bvv[g]);
}

// ---------------- K3: S2 = K̂ᵀK̂ and ksum = Σ k̂ ----------------
extern "C" __global__ __launch_bounds__(256)
void s2k(const u16* __restrict__ khb, float* __restrict__ S2,
         float* __restrict__ ksum)
{
    __shared__ float ks[36][33];
    const int t = threadIdx.x;
    const int m0 = blockIdx.x * 36;
    if (t < 144){
        const int row = t >> 2, seg = (t & 3) * 8;
        bf16x8 v = *reinterpret_cast<const bf16x8*>(khb + (m0 + row) * 32 + seg);
        #pragma unroll
        for (int j = 0; j < 8; ++j)
            ks[row][seg + j] = bf2f((u16)v[j]);
    }
    __syncthreads();
    #pragma unroll
    for (int k2 = 0; k2 < 4; ++k2){
        const int task = t + 256 * k2;
        const int i = task >> 5, j = task & 31;
        float s = 0.f;
        for (int m = 0; m < 36; ++m)
            s = fmaf(ks[m][i], ks[m][j], s);
        atomicAdd(S2 + task, s);
    }
    if (t < 32){
        float s = 0.f;
        for (int m = 0; m < 36; ++m) s += ks[m][t];
        atomicAdd(ksum + t, s);
    }
}

// ---------------- K4: per-row Taylor rowsum -> rinv ----------------
extern "C" __global__ __launch_bounds__(256)
void rowfin(const u16* __restrict__ qhb, const float* __restrict__ S2,
            const float* __restrict__ ksum,
            const float* __restrict__ pq, const float* __restrict__ pk,
            float* __restrict__ rinv_arr)
{
    __shared__ float s2s[1024];
    __shared__ float kss[32];
    const int t = threadIdx.x;
    #pragma unroll
    for (int k2 = 0; k2 < 4; ++k2) s2s[t + 256*k2] = S2[t + 256*k2];
    if (t < 32) kss[t] = ksum[t];
    __syncthreads();

    float sq = 0.f, sk = 0.f;
    for (int i = 0; i < 72; ++i){ sq += pq[i]; sk += pk[i]; }
    const float d = rsqrtf(sq) * rsqrtf(sk);

    const int n = blockIdx.x * 256 + t;
    float q[32];
    #pragma unroll
    for (int s8 = 0; s8 < 4; ++s8){
        bf16x8 v = *reinterpret_cast<const bf16x8*>(qhb + n * 32 + s8 * 8);
        #pragma unroll
        for (int j = 0; j < 8; ++j) q[s8*8 + j] = bf2f((u16)v[j]);
    }
    float d1 = 0.f;
    #pragma unroll
    for (int o = 0; o < 32; ++o) d1 = fmaf(q[o], kss[o], d1);
    float quad = 0.f;
    for (int o = 0; o < 32; ++o){
        float s = 0.f;
        #pragma unroll
        for (int j = 0; j < 32; ++j) s = fmaf(s2s[o*32 + j], q[j], s);
        quad = fmaf(q[o], s, quad);
    }
    const float rs = 9216.f + d1 * d + 0.5f * quad * d * d;
    rinv_arr[n] = 1.f / rs;
}

// ---------------- K5: attention write + PV ----------------
// grid 1152: nc = bid>>3 (64 n-rows), ms = bid&7 (1152 m-cols)
// 5 periods of m: 4x256 + 1x128. Unnormalized P in LDS; rinv applied at write.
extern "C" __global__ __launch_bounds__(256, 3)
void attn_main(const u16* __restrict__ qhb, const u16* __restrict__ khb,
               const u16* __restrict__ vb,
               const float* __restrict__ pq, const float* __restrict__ pk,
               const float* __restrict__ rinv_arr,
               float* __restrict__ outdst, float* __restrict__ attnf,
               int use_atomic)
{
    __shared__ u16 ps[64 * PS2];
    __shared__ float rsl[64];
    const int bid = blockIdx.x;
    const int nc = bid >> 3, ms = bid & 7;
    const int t = threadIdx.x, w = t >> 6, l = t & 63, h = l >> 4, r = l & 15;
    const int n0 = nc * 64, mbase = ms * 1152;

    float sq = 0.f, sk = 0.f;
    for (int i = 0; i < 72; ++i){ sq += pq[i]; sk += pk[i]; }
    const float inv_den = rsqrtf(sq) * rsqrtf(sk);

    if (t < 64) rsl[t] = rinv_arr[n0 + t];

    bf16x8 qf[4];
    #pragma unroll
    for (int nt = 0; nt < 4; ++nt)
        qf[nt] = *reinterpret_cast<const bf16x8*>(qhb + (size_t)(n0 + nt*16 + r)*32 + 8*h);

    f32x4 acc[4][4];
    #pragma unroll
    for (int ct = 0; ct < 4; ++ct)
        #pragma unroll
        for (int nt = 0; nt < 4; ++nt)
            acc[ct][nt] = (f32x4){0.f,0.f,0.f,0.f};

    for (int p = 0; p < 5; ++p){
        const int m0 = mbase + p * 256;
        const int span = (p < 4) ? 256 : 128;

        // STAGE: QK -> Taylor exp (unnormalized) -> ps
        for (int k64 = 0; k64 < (span >> 6); ++k64){
            bf16x8 kf = *reinterpret_cast<const bf16x8*>(
                khb + (size_t)(m0 + k64*64 + w*16 + r)*32 + 8*h);
            #pragma unroll
            for (int nt = 0; nt < 4; ++nt){
                f32x4 z = {0.f,0.f,0.f,0.f};
                f32x4 e = __builtin_amdgcn_mfma_f32_16x16x32_bf16(qf[nt], kf, z, 0,0,0);
                #pragma unroll
                for (int g = 0; g < 4; ++g){
                    float ep = e[g] * inv_den;
                    float pt = fmaf(ep, fmaf(0.5f, ep, 1.f), 1.f);
                    ps[(nt*16 + 4*h + g) * PS2 + k64*64 + w*16 + r] = f2bf(pt);
                }
            }
        }
        __syncthreads();

        // attention write: wave rows w+4j, 1KB contiguous per wave-store
        #pragma unroll 4
        for (int j = 0; j < 16; ++j){
            const int row = w + 4*j;
            const float rv = rsl[row];
            if (l * 4 < span){
                ushort4 u = *reinterpret_cast<const ushort4*>(&ps[row * PS2 + l*4]);
                float4 f4;
                f4.x = bf2f(u.x) * rv; f4.y = bf2f(u.y) * rv;
                f4.z = bf2f(u.z) * rv; f4.w = bf2f(u.w) * rv;
                *reinterpret_cast<float4*>(attnf + (size_t)(n0 + row) * NN + m0 + l*4) = f4;
            }
        }

        // PV over this period
        for (int ksl = 0; ksl < (span >> 5); ++ksl){
            bf16x8 av[4];
            #pragma unroll
            for (int ct = 0; ct < 4; ++ct)
                av[ct] = *reinterpret_cast<const bf16x8*>(
                    vb + (size_t)(w*64 + ct*16 + r) * NN + m0 + ksl*32 + 8*h);
            bf16x8 bv2[4];
            #pragma unroll
            for (int nt = 0; nt < 4; ++nt)
                bv2[nt] = *reinterpret_cast<const bf16x8*>(
                    &ps[(nt*16 + r) * PS2 + ksl*32 + 8*h]);
            #pragma unroll
            for (int ct = 0; ct < 4; ++ct)
                #pragma unroll
                for (int nt = 0; nt < 4; ++nt)
                    acc[ct][nt] = __builtin_amdgcn_mfma_f32_16x16x32_bf16(
                        av[ct], bv2[nt], acc[ct][nt], 0,0,0);
        }
        __syncthreads();
    }

    float rvv[4];
    #pragma unroll
    for (int nt = 0; nt < 4; ++nt) rvv[nt] = rsl[nt*16 + r];

    if (!use_atomic){
        float* dst = outdst + (size_t)ms * (CCH * NN);
        #pragma unroll
        for (int ct = 0; ct < 4; ++ct)
            #pragma unroll
            for (int nt = 0; nt < 4; ++nt)
                #pragma unroll
                for (int g = 0; g < 4; ++g)
                    dst[(size_t)(w*64 + ct*16 + 4*h + g) * NN + n0 + nt*16 + r] =
                        acc[ct][nt][g] * rvv[nt];
    } else {
        #pragma unroll
        for (int ct = 0; ct < 4; ++ct)
            #pragma unroll
            for (int nt = 0; nt < 4; ++nt)
                #pragma unroll
                for (int g = 0; g < 4; ++g)
                    atomicAdd(outdst + (size_t)(w*64 + ct*16 + 4*h + g) * NN + n0 + nt*16 + r,
                              acc[ct][nt][g] * rvv[nt]);
    }
}

// ---------------- K6: out = gamma*(sum partials) + x ----------------
extern "C" __global__ __launch_bounds__(256)
void epilogue(const float* __restrict__ x, const float* __restrict__ gm,
              const float* __restrict__ parts, int nparts,
              float* __restrict__ outf)
{
    const float g = gm[0];
    const size_t i = ((size_t)blockIdx.x * 256 + threadIdx.x) * 4;
    float4 a;
    if (nparts > 0){
        a.x = a.y = a.z = a.w = 0.f;
        for (int s = 0; s < nparts; ++s){
            float4 p = *reinterpret_cast<const float4*>(parts + (size_t)s * (CCH*NN) + i);
            a.x += p.x; a.y += p.y; a.z += p.z; a.w += p.w;
        }
    } else {
        a = *reinterpret_cast<float4*>(outf + i);
    }
    float4 xv = *reinterpret_cast<const float4*>(x + i);
    a.x = fmaf(g, a.x, xv.x);
    a.y = fmaf(g, a.y, xv.y);
    a.z = fmaf(g, a.z, xv.z);
    a.w = fmaf(g, a.w, xv.w);
    *reinterpret_cast<float4*>(outf + i) = a;
}

extern "C" __global__ __launch_bounds__(256)
void zero_buf(float* __restrict__ p)
{
    float4 z = {0.f,0.f,0.f,0.f};
    *reinterpret_cast<float4*>(p + ((size_t)blockIdx.x * 256 + threadIdx.x) * 4) = z;
}

extern "C" void kernel_launch(void* const* d_in, const int* in_sizes, int n_in,
                              void* d_out, int out_size, void* d_ws, size_t ws_size,
                              hipStream_t stream)
{
    (void)in_sizes; (void)n_in; (void)out_size;
    const float* x  = (const float*)d_in[0];
    const float* sf = (const float*)d_in[1];
    const float* Wq = (const float*)d_in[2];
    const float* bq = (const float*)d_in[3];
    const float* Wk = (const float*)d_in[4];
    const float* bk = (const float*)d_in[5];
    const float* Wv = (const float*)d_in[6];
    const float* bv = (const float*)d_in[7];
    const float* gm = (const float*)d_in[8];

    float* outf  = (float*)d_out;                       // [256][9216] f32
    float* attnf = outf + (size_t)256 * 9216;           // [9216][9216] f32

    char* ws = (char*)d_ws;
    u16*   xT    = (u16*)(ws);                          //  4,718,592
    u16*   sfT   = (u16*)(ws +  4718592);               //  4,718,592
    u16*   wqb   = (u16*)(ws +  9437184);               //     16,384
    u16*   wkb   = (u16*)(ws +  9453568);               //     16,384
    u16*   wvb   = (u16*)(ws +  9469952);               //    131,072
    u16*   qhb   = (u16*)(ws +  9601024);               //    589,824
    u16*   khb   = (u16*)(ws + 10190848);               //    589,824
    u16*   vbp   = (u16*)(ws + 10780672);               //  4,718,592
    float* pq    = (float*)(ws + 15499264);             //        288
    float* pk    = (float*)(ws + 15499552);             //        288
    float* S2    = (float*)(ws + 15499840);             //      4,096
    float* ksum  = (float*)(ws + 15503936);             //        128
    float* rinv  = (float*)(ws + 15504064);             //     36,864
    float* parts = (float*)(ws + 15540928);             // 8 × 9,437,184
    const size_t need = 15540928ull + 8ull * 9437184ull;

    const bool use_parts = (ws_size >= need);

    castT   <<<dim3(296),  dim3(256), 0, stream>>>(x, sf, Wq, Wk, Wv,
                                                   xT, sfT, wqb, wkb, wvb, S2, ksum);
    qk_gemm <<<dim3(72),   dim3(256), 0, stream>>>(xT, sfT, wqb, wkb, bq, bk,
                                                   qhb, khb, pq, pk);
    v_gemm  <<<dim3(576),  dim3(256), 0, stream>>>(xT, wvb, bv, vbp);
    s2k     <<<dim3(256),  dim3(256), 0, stream>>>(khb, S2, ksum);
    rowfin  <<<dim3(36),   dim3(256), 0, stream>>>(qhb, S2, ksum, pq, pk, rinv);
    if (!use_parts)
        zero_buf<<<dim3(2304), dim3(256), 0, stream>>>(outf);
    attn_main<<<dim3(1152), dim3(256), 0, stream>>>(qhb, khb, vbp, pq, pk, rinv,
                                                    use_parts ? parts : outf, attnf,
                                                    use_parts ? 0 : 1);
    epilogue <<<dim3(2304), dim3(256), 0, stream>>>(x, gm, parts,
                                                    use_parts ? 8 : 0, outf);
}